// Round 4
// baseline (560.463 us; speedup 1.0000x reference)
//
#include <hip/hip_runtime.h>
#include <cstdint>
#include <cstddef>

typedef unsigned short u16;
typedef __bf16 bf16x8 __attribute__((ext_vector_type(8)));
typedef float f32x4 __attribute__((ext_vector_type(4)));

// q is pre-scaled by 1/sqrt(64) * log2(e) so flash softmax runs in exp2 domain
#define SCALE_Q_LOG2E 0.18033688011112042f

static __device__ __forceinline__ float b2f(u16 u){ return __uint_as_float(((unsigned)u)<<16); }
static __device__ __forceinline__ u16 f2b(float f){
  unsigned u = __float_as_uint(f);
  return (u16)((u + 0x7fffu + ((u>>16)&1u)) >> 16);
}
// async global->LDS, 16 B per lane; LDS dest is wave-uniform base + lane*16
static __device__ __forceinline__ void gload_lds16(const void* g, void* l){
  auto gp = reinterpret_cast<__attribute__((address_space(1))) uint32_t*>(reinterpret_cast<uintptr_t>(g));
  auto lp = reinterpret_cast<__attribute__((address_space(3))) uint32_t*>(reinterpret_cast<uintptr_t>(l));
  __builtin_amdgcn_global_load_lds(gp, lp, 16, 0, 0);
}

// ---------------- weight transpose f32 -> bf16, 32x32 tiles ----------------
// rowmap: 0 = identity; 1 = w1-interleave (out_row = (c>>4)*32 + (c&15));
//         2 = w3-interleave (out_row = (c>>4)*32 + 16 + (c&15))
__global__ __launch_bounds__(256) void transpose_f2b(const float* __restrict__ in, u16* __restrict__ out,
                                                     int R, int C, int rowmap){
  __shared__ float tile[32][33];
  int tx = threadIdx.x, ty = threadIdx.y;
  int c0 = blockIdx.x*32, r0 = blockIdx.y*32;
  #pragma unroll
  for (int i=0;i<4;i++) tile[ty+i*8][tx] = in[(size_t)(r0+ty+i*8)*C + c0+tx];
  __syncthreads();
  #pragma unroll
  for (int i=0;i<4;i++){
    int c = c0+ty+i*8;
    int orow = c;
    if (rowmap==1) orow = (c>>4)*32 + (c&15);
    else if (rowmap==2) orow = (c>>4)*32 + 16 + (c&15);
    out[(size_t)orow*R + r0+tx] = f2b(tile[tx][ty+i*8]);
  }
}

// ---------------- bf16 raw transpose (for V), batched over z ----------------
__global__ __launch_bounds__(256) void transpose_bf16(const u16* __restrict__ in, u16* __restrict__ out,
                                                      int R, int C){
  __shared__ u16 tile[32][33];
  size_t zoff = (size_t)blockIdx.z * R * C;
  const u16* ip = in + zoff;
  u16* op = out + zoff;
  int tx = threadIdx.x, ty = threadIdx.y;
  int c0 = blockIdx.x*32, r0 = blockIdx.y*32;
  #pragma unroll
  for (int i=0;i<4;i++) tile[ty+i*8][tx] = ip[(size_t)(r0+ty+i*8)*C + c0+tx];
  __syncthreads();
  #pragma unroll
  for (int i=0;i<4;i++) op[(size_t)(c0+ty+i*8)*R + r0+tx] = tile[tx][ty+i*8];
}

// ---------------- router logits: one wave per row (f32) ----------------
__global__ __launch_bounds__(256) void router_kernel(const float* __restrict__ x, const float* __restrict__ wr,
                                                     float* __restrict__ logits){
  int row = blockIdx.x*4 + (threadIdx.x>>6);
  int l = threadIdx.x & 63;
  const float4* xr = (const float4*)(x + (size_t)row*1024) + l;
  const float4* wp = (const float4*)wr + l;
  float acc = 0.f;
  #pragma unroll
  for (int c=0;c<4;c++){
    float4 xv = xr[c*64];
    float4 wv = wp[c*64];
    acc += xv.x*wv.x + xv.y*wv.y + xv.z*wv.z + xv.w*wv.w;
  }
  #pragma unroll
  for (int m=1;m<64;m<<=1) acc += __shfl_xor(acc, m, 64);
  if (l==0) logits[row] = acc;
}

// ---------------- exact top-K (radix select) + softmax weights + inverse map ----------------
static __device__ __forceinline__ unsigned mapkey(float f){
  unsigned u = __float_as_uint(f);
  return (u & 0x80000000u) ? ~u : (u | 0x80000000u);   // monotone: bigger float -> bigger key
}
static __device__ unsigned blk_scan_excl(unsigned cnt, unsigned* swav){
  int t = threadIdx.x; int l = t&63, w = t>>6;
  unsigned v = cnt;
  #pragma unroll
  for (int off=1; off<64; off<<=1){
    unsigned n = __shfl_up(v, off, 64);
    if (l >= off) v += n;
  }
  __syncthreads();
  if (l==63) swav[w] = v;
  __syncthreads();
  if (t==0){ unsigned c=0; for (int i=0;i<16;i++){ unsigned tmp=swav[i]; swav[i]=c; c+=tmp; } }
  __syncthreads();
  return swav[w] + v - cnt;
}
__global__ __launch_bounds__(1024) void topk_kernel(const float* __restrict__ logits,
        int* __restrict__ sel, float* __restrict__ rw, int* __restrict__ inv){
  int b = blockIdx.x, t = threadIdx.x;
  int l = t&63, w = t>>6;
  __shared__ float vals[4096];
  __shared__ unsigned hist[256];
  __shared__ unsigned swav[16];
  __shared__ float fwav[16];
  __shared__ unsigned sh_prefix, sh_remaining;
  const float* lgp = logits + b*4096;
  for (int i=t;i<4096;i+=1024) vals[i]=lgp[i];
  if (t==0){ sh_prefix=0u; sh_remaining=2048u; }
  __syncthreads();
  for (int level=0; level<4; level++){
    int shift = 24 - level*8;
    if (t<256) hist[t]=0u;
    __syncthreads();
    unsigned pfx = sh_prefix;
    for (int i=t;i<4096;i+=1024){
      unsigned key = mapkey(vals[i]);
      if (level==0 || (key >> (shift+8)) == pfx)
        atomicAdd(&hist[(key>>shift)&255u], 1u);
    }
    __syncthreads();
    if (t==0){
      unsigned rem = sh_remaining, cum=0u; unsigned bsel=0u;
      for (int bin=255; bin>=0; bin--){
        unsigned hc = hist[bin];
        if (cum + hc >= rem){ bsel=(unsigned)bin; break; }
        cum += hc;
      }
      sh_remaining = rem - cum;
      sh_prefix = (pfx<<8) | bsel;
    }
    __syncthreads();
  }
  unsigned T = sh_prefix;       // key of the 2048-th largest
  unsigned req = sh_remaining;  // how many ==T to take (lowest index first, matches top_k)
  int i0 = t*4;
  unsigned gt_[4], eq_[4], fl_[4]; float v_[4];
  #pragma unroll
  for (int j=0;j<4;j++){
    v_[j] = vals[i0+j];
    unsigned key = mapkey(v_[j]);
    gt_[j] = key > T ? 1u:0u;
    eq_[j] = key == T ? 1u:0u;
  }
  unsigned eqbase = blk_scan_excl(eq_[0]+eq_[1]+eq_[2]+eq_[3], swav);
  unsigned er = eqbase;
  #pragma unroll
  for (int j=0;j<4;j++){ fl_[j] = gt_[j] | (eq_[j] & (er < req ? 1u:0u)); er += eq_[j]; }
  unsigned pbase = blk_scan_excl(fl_[0]+fl_[1]+fl_[2]+fl_[3], swav);
  unsigned p = pbase;
  #pragma unroll
  for (int j=0;j<4;j++){
    int i = i0+j;
    if (fl_[j]){ sel[b*2048+(int)p]=i; inv[b*4096+i]=(int)p; p++; }
    else inv[b*4096+i] = -1;
  }
  // softmax over selected logits (global max is always selected: it is top-1)
  float mx = fmaxf(fmaxf(v_[0],v_[1]), fmaxf(v_[2],v_[3]));
  #pragma unroll
  for (int m=1;m<64;m<<=1) mx = fmaxf(mx, __shfl_xor(mx,m,64));
  __syncthreads();
  if (l==0) fwav[w]=mx;
  __syncthreads();
  if (t==0){ float g=fwav[0]; for(int i=1;i<16;i++) g=fmaxf(g,fwav[i]); fwav[0]=g; }
  __syncthreads();
  float gm = fwav[0];
  float zz = 0.f;
  #pragma unroll
  for (int j=0;j<4;j++) if (fl_[j]) zz += expf(v_[j]-gm);
  #pragma unroll
  for (int m=1;m<64;m<<=1) zz += __shfl_xor(zz,m,64);
  __syncthreads();
  if (l==0) fwav[w]=zz;
  __syncthreads();
  if (t==0){ float s=0.f; for(int i=0;i<16;i++) s+=fwav[i]; fwav[0]=s; }
  __syncthreads();
  float Z = fwav[0];
  unsigned p2 = pbase;
  #pragma unroll
  for (int j=0;j<4;j++) if (fl_[j]){ rw[b*2048+(int)p2] = expf(v_[j]-gm)/Z; p2++; }
}

// ---------------- (gathered) RMSNorm f32 -> bf16 ----------------
__global__ __launch_bounds__(256) void rmsnorm_kernel(const float* __restrict__ xin,
        const float* __restrict__ gamma, const int* __restrict__ sel,
        u16* __restrict__ xn){
  int r = blockIdx.x;
  int src = r;
  if (sel) src = (r>>11)*4096 + sel[r];
  const float* row = xin + (size_t)src*1024;
  int t = threadIdx.x, l = t&63, w = t>>6;
  int d0 = t*4;
  float4 xv = *(const float4*)(row + d0);
  float ss = xv.x*xv.x + xv.y*xv.y + xv.z*xv.z + xv.w*xv.w;
  #pragma unroll
  for (int m=1;m<64;m<<=1) ss += __shfl_xor(ss,m,64);
  __shared__ float red[4];
  if (l==0) red[w]=ss;
  __syncthreads();
  float tot = red[0]+red[1]+red[2]+red[3];
  float rms = rsqrtf(tot*(1.f/1024.f) + 1e-5f);
  float4 gv = *(const float4*)(gamma + d0);
  u16 o0=f2b(xv.x*rms*gv.x), o1=f2b(xv.y*rms*gv.y), o2=f2b(xv.z*rms*gv.z), o3=f2b(xv.w*rms*gv.w);
  uint2 ov; ov.x = (unsigned)o0 | ((unsigned)o1<<16); ov.y = (unsigned)o2 | ((unsigned)o3<<16);
  *(uint2*)(xn + (size_t)r*1024 + d0) = ov;
}

// ---------------- generic m97-style GEMM: C = A(128xK) * Bt(BNxK)^T (+resid/gather) ----------------
template<int BN, typename OT>
__global__ __launch_bounds__(256,2) void gemm_bt(const u16* __restrict__ A, const u16* __restrict__ Bt,
        OT* __restrict__ C, const float* __restrict__ resid, const int* __restrict__ sel,
        int M, int N, int Kd){
  __shared__ u16 As[128*32];
  __shared__ u16 Bs[BN*32];
  constexpr int NF = BN/32;
  int t = threadIdx.x, w = t>>6, l = t&63, lg = l>>4, ln = l&15;
  int m0 = blockIdx.y*128, n0 = blockIdx.x*BN;
  int wm = (w&1)*64, wn = (w>>1)*(BN/2);
  f32x4 acc[4][NF] = {};
  for (int k0=0; k0<Kd; k0+=32){
    __syncthreads();
    #pragma unroll
    for (int c=0;c<2;c++){
      int off = t*16 + c*4096;
      int row = off>>6, ku = (off&63)>>1;
      gload_lds16(A  + (size_t)(m0+row)*Kd + k0 + ku, &As[w*512 + c*2048]);
    }
    #pragma unroll
    for (int c=0;c<BN/64;c++){
      int off = t*16 + c*4096;
      int row = off>>6, ku = (off&63)>>1;
      gload_lds16(Bt + (size_t)(n0+row)*Kd + k0 + ku, &Bs[w*512 + c*2048]);
    }
    __syncthreads();
    bf16x8 af[4], bfv[NF];
    #pragma unroll
    for (int i=0;i<4;i++) af[i]  = *(const bf16x8*)&As[(wm+i*16+ln)*32 + lg*8];
    #pragma unroll
    for (int i=0;i<NF;i++) bfv[i] = *(const bf16x8*)&Bs[(wn+i*16+ln)*32 + lg*8];
    #pragma unroll
    for (int mi=0;mi<4;mi++)
      #pragma unroll
      for (int ni=0;ni<NF;ni++)
        acc[mi][ni] = __builtin_amdgcn_mfma_f32_16x16x32_bf16(af[mi], bfv[ni], acc[mi][ni], 0,0,0);
  }
  #pragma unroll
  for (int mi=0;mi<4;mi++){
    #pragma unroll
    for (int ni=0;ni<NF;ni++){
      #pragma unroll
      for (int r=0;r<4;r++){
        int row = m0+wm+mi*16+lg*4+r;
        int col = n0+wn+ni*16+ln;
        float v = acc[mi][ni][r];
        if (resid){
          size_t rrow = sel ? ((size_t)(row>>11)*4096 + sel[row]) : (size_t)row;
          v += resid[rrow*N + col];
        }
        if constexpr (sizeof(OT)==2) C[(size_t)row*N + col] = f2b(v);
        else                          C[(size_t)row*N + col] = v;
      }
    }
  }
}

// ---------------- QKV GEMM with fused RoPE epilogue ----------------
// Writes q_r/k_r/v_r in [b,h,tok,64] layout; q pre-scaled by 1/8*log2e.
__global__ __launch_bounds__(256,2) void gemm_qkv(const u16* __restrict__ A, const u16* __restrict__ Bt,
        const float* __restrict__ fcos, const float* __restrict__ fsin,
        u16* __restrict__ q_r, u16* __restrict__ k_r, u16* __restrict__ v_r, int Kd){
  __shared__ u16 As[128*32];
  __shared__ u16 Bs[128*32];
  int t = threadIdx.x, w = t>>6, l = t&63, lg = l>>4, ln = l&15;
  int m0 = blockIdx.y*128, n0 = blockIdx.x*128;
  int wm = (w&1)*64, wn = (w>>1)*64;
  f32x4 acc[4][4] = {};
  for (int k0=0; k0<Kd; k0+=32){
    __syncthreads();
    #pragma unroll
    for (int c=0;c<2;c++){
      int off = t*16 + c*4096;
      int row = off>>6, ku = (off&63)>>1;
      gload_lds16(A  + (size_t)(m0+row)*Kd + k0 + ku, &As[w*512 + c*2048]);
      gload_lds16(Bt + (size_t)(n0+row)*Kd + k0 + ku, &Bs[w*512 + c*2048]);
    }
    __syncthreads();
    bf16x8 af[4], bfv[4];
    #pragma unroll
    for (int i=0;i<4;i++){
      af[i]  = *(const bf16x8*)&As[(wm+i*16+ln)*32 + lg*8];
      bfv[i] = *(const bf16x8*)&Bs[(wn+i*16+ln)*32 + lg*8];
    }
    #pragma unroll
    for (int mi=0;mi<4;mi++)
      #pragma unroll
      for (int ni=0;ni<4;ni++)
        acc[mi][ni] = __builtin_amdgcn_mfma_f32_16x16x32_bf16(af[mi], bfv[ni], acc[mi][ni], 0,0,0);
  }
  #pragma unroll
  for (int ni=0;ni<4;ni++){
    int col = n0+wn+ni*16+ln;        // 0..3071
    int sect = col>>10;              // 0=q 1=k 2=v (uniform per ni)
    int d = col & 1023;
    int h = d>>6, wd = d&63, ii = wd>>1;
    #pragma unroll
    for (int mi=0;mi<4;mi++){
      #pragma unroll
      for (int r=0;r<4;r++){
        int row = m0+wm+mi*16+lg*4+r;   // b*2048+tok
        int b = row>>11, tok = row&2047;
        float v = acc[mi][ni][r];
        float pv = __shfl_xor(v, 1, 64);  // partner lane holds the other half of the rope pair
        size_t ob = (((size_t)b*16+h)*2048 + tok)*64 + wd;
        if (sect==2){
          v_r[ob] = f2b(v);
        } else {
          float c = fcos[tok*32+ii], s = fsin[tok*32+ii];
          float o = (wd&1) ? (pv*s + v*c) : (v*c - pv*s);
          if (sect==0) q_r[ob] = f2b(o*SCALE_Q_LOG2E);
          else         k_r[ob] = f2b(o);
        }
      }
    }
  }
}

// ---------------- FFN13 GEMM with fused SwiGLU epilogue ----------------
// Bt = W13T interleaved: row r -> (r&31)<16 ? w1 col 16*(r>>5)+(r&31) : w3 col 16*(r>>5)+(r&31)-16.
// ni even frag = a1, ni odd frag = a3 for the same 16 g-columns. g is M x 4096.
__global__ __launch_bounds__(256,2) void gemm13(const u16* __restrict__ A, const u16* __restrict__ Bt,
        u16* __restrict__ g, int Kd){
  __shared__ u16 As[128*32];
  __shared__ u16 Bs[128*32];
  int t = threadIdx.x, w = t>>6, l = t&63, lg = l>>4, ln = l&15;
  int m0 = blockIdx.y*128, n0 = blockIdx.x*128;
  int wm = (w&1)*64, wn = (w>>1)*64;
  f32x4 acc[4][4] = {};
  for (int k0=0; k0<Kd; k0+=32){
    __syncthreads();
    #pragma unroll
    for (int c=0;c<2;c++){
      int off = t*16 + c*4096;
      int row = off>>6, ku = (off&63)>>1;
      gload_lds16(A  + (size_t)(m0+row)*Kd + k0 + ku, &As[w*512 + c*2048]);
      gload_lds16(Bt + (size_t)(n0+row)*Kd + k0 + ku, &Bs[w*512 + c*2048]);
    }
    __syncthreads();
    bf16x8 af[4], bfv[4];
    #pragma unroll
    for (int i=0;i<4;i++){
      af[i]  = *(const bf16x8*)&As[(wm+i*16+ln)*32 + lg*8];
      bfv[i] = *(const bf16x8*)&Bs[(wn+i*16+ln)*32 + lg*8];
    }
    #pragma unroll
    for (int mi=0;mi<4;mi++)
      #pragma unroll
      for (int ni=0;ni<4;ni++)
        acc[mi][ni] = __builtin_amdgcn_mfma_f32_16x16x32_bf16(af[mi], bfv[ni], acc[mi][ni], 0,0,0);
  }
  int gbase = (n0+wn)>>1;    // g column base for this wave
  #pragma unroll
  for (int mi=0;mi<4;mi++){
    #pragma unroll
    for (int p=0;p<2;p++){
      #pragma unroll
      for (int r=0;r<4;r++){
        int row = m0+wm+mi*16+lg*4+r;
        int col = gbase + p*16 + ln;
        float a1 = acc[mi][2*p][r], a3 = acc[mi][2*p+1][r];
        float s1 = a1 / (1.f + __expf(-a1));
        g[(size_t)row*4096 + col] = f2b(s1*a3);
      }
    }
  }
}

// ---------------- flash attention, causal, HD=64 ----------------
__global__ __launch_bounds__(256,2) void flash_kernel(const u16* __restrict__ q_r,
        const u16* __restrict__ k_r, const u16* __restrict__ v_t, u16* __restrict__ o){
  const int S = 2048;
  int pr = blockIdx.x, bh = blockIdx.y;
  int b = bh>>4, h = bh&15;
  int t = threadIdx.x, w = t>>6, l = t&63, lg = l>>4, ln = l&15;
  __shared__ u16 Ks[2][64*72];   // [token][dim], stride 72
  __shared__ u16 Vs[2][64*72];   // [dim][token]
  __shared__ u16 Ps[4][16*72];   // per-wave P round-trip (intra-wave only)
  const u16* qb = q_r + (size_t)bh*S*64;
  const u16* kb = k_r + (size_t)bh*S*64;
  const u16* vb = v_t + (size_t)bh*64*S;
  int rr = t>>2, p16 = (t&3)*16;
  #pragma unroll
  for (int ti=0; ti<2; ti++){
    int qt = ti ? (31-pr) : pr;
    int q0 = qt*64;
    bf16x8 qf0 = *(const bf16x8*)(qb + (size_t)(q0 + w*16 + ln)*64 + lg*8);
    bf16x8 qf1 = *(const bf16x8*)(qb + (size_t)(q0 + w*16 + ln)*64 + 32 + lg*8);
    f32x4 oacc[4] = {};
    float mi_[4], li_[4];
    #pragma unroll
    for (int r=0;r<4;r++){ mi_[r]=-1e30f; li_[r]=0.f; }
    __syncthreads();
    {
      *(bf16x8*)&Ks[0][rr*72+p16]   = *(const bf16x8*)(kb + (size_t)rr*64 + p16);
      *(bf16x8*)&Ks[0][rr*72+p16+8] = *(const bf16x8*)(kb + (size_t)rr*64 + p16 + 8);
      *(bf16x8*)&Vs[0][rr*72+p16]   = *(const bf16x8*)(vb + (size_t)rr*S + p16);
      *(bf16x8*)&Vs[0][rr*72+p16+8] = *(const bf16x8*)(vb + (size_t)rr*S + p16 + 8);
    }
    __syncthreads();
    for (int kv=0; kv<=qt; kv++){
      int cur = kv&1;
      int k0 = kv*64;
      bool hasnext = kv < qt;
      bf16x8 nk0, nk1, nv0, nv1;
      if (hasnext){
        int kn = k0 + 64;
        nk0 = *(const bf16x8*)(kb + (size_t)(kn+rr)*64 + p16);
        nk1 = *(const bf16x8*)(kb + (size_t)(kn+rr)*64 + p16 + 8);
        nv0 = *(const bf16x8*)(vb + (size_t)rr*S + kn + p16);
        nv1 = *(const bf16x8*)(vb + (size_t)rr*S + kn + p16 + 8);
      }
      f32x4 sv[4];
      #pragma unroll
      for (int ni=0;ni<4;ni++){
        bf16x8 kf0 = *(const bf16x8*)&Ks[cur][(ni*16+ln)*72 + lg*8];
        bf16x8 kf1 = *(const bf16x8*)&Ks[cur][(ni*16+ln)*72 + 32 + lg*8];
        f32x4 z = {};
        z = __builtin_amdgcn_mfma_f32_16x16x32_bf16(qf0, kf0, z, 0,0,0);
        z = __builtin_amdgcn_mfma_f32_16x16x32_bf16(qf1, kf1, z, 0,0,0);
        sv[ni] = z;
      }
      bool diag = (kv==qt);
      float pm[4][4], alpha[4];
      #pragma unroll
      for (int r=0;r<4;r++){
        int qrow = q0 + w*16 + lg*4 + r;
        float rm = -1e30f;
        #pragma unroll
        for (int ni=0;ni<4;ni++){
          float xs = sv[ni][r];
          if (diag && (k0+ni*16+ln) > qrow) xs = -1e30f;
          sv[ni][r] = xs;
          rm = fmaxf(rm, xs);
        }
        #pragma unroll
        for (int m=1;m<16;m<<=1) rm = fmaxf(rm, __shfl_xor(rm,m,64));
        float mn = fmaxf(mi_[r], rm);
        alpha[r] = exp2f(mi_[r] - mn);
        float ls = 0.f;
        #pragma unroll
        for (int ni=0;ni<4;ni++){ float pp = exp2f(sv[ni][r]-mn); pm[ni][r]=pp; ls+=pp; }
        #pragma unroll
        for (int m=1;m<16;m<<=1) ls += __shfl_xor(ls,m,64);
        li_[r] = li_[r]*alpha[r] + ls;
        mi_[r] = mn;
      }
      asm volatile("" ::: "memory");
      #pragma unroll
      for (int ni=0;ni<4;ni++)
        #pragma unroll
        for (int r=0;r<4;r++)
          Ps[w][(lg*4+r)*72 + ni*16 + ln] = f2b(pm[ni][r]);
      asm volatile("" ::: "memory");
      bf16x8 pf0 = *(const bf16x8*)&Ps[w][ln*72 + lg*8];
      bf16x8 pf1 = *(const bf16x8*)&Ps[w][ln*72 + 32 + lg*8];
      #pragma unroll
      for (int dt=0; dt<4; dt++){
        bf16x8 vf0 = *(const bf16x8*)&Vs[cur][(dt*16+ln)*72 + lg*8];
        bf16x8 vf1 = *(const bf16x8*)&Vs[cur][(dt*16+ln)*72 + 32 + lg*8];
        f32x4 oo = oacc[dt];
        #pragma unroll
        for (int r=0;r<4;r++) oo[r] *= alpha[r];
        oo = __builtin_amdgcn_mfma_f32_16x16x32_bf16(pf0, vf0, oo, 0,0,0);
        oo = __builtin_amdgcn_mfma_f32_16x16x32_bf16(pf1, vf1, oo, 0,0,0);
        oacc[dt] = oo;
      }
      if (hasnext){
        int nb = cur^1;
        *(bf16x8*)&Ks[nb][rr*72+p16]   = nk0;
        *(bf16x8*)&Ks[nb][rr*72+p16+8] = nk1;
        *(bf16x8*)&Vs[nb][rr*72+p16]   = nv0;
        *(bf16x8*)&Vs[nb][rr*72+p16+8] = nv1;
      }
      __syncthreads();
    }
    #pragma unroll
    for (int dt=0; dt<4; dt++){
      #pragma unroll
      for (int r=0;r<4;r++){
        int tok = q0 + w*16 + lg*4 + r;
        int dim = dt*16 + ln;
        o[((size_t)(b*S+tok))*1024 + h*64 + dim] = f2b(oacc[dt][r] / li_[r]);
      }
    }
  }
}

// ---------------- out = x (+ rw * (h + y) on selected rows), f32 out ----------------
__global__ __launch_bounds__(256) void final_kernel(const float* __restrict__ x, const float* __restrict__ h,
        const u16* __restrict__ y, const int* __restrict__ inv, const float* __restrict__ rw,
        float* __restrict__ out){
  int row = blockIdx.x;
  int b = row>>12;
  int t = threadIdx.x, d0 = t*4;
  float4 xv = *(const float4*)(x + (size_t)row*1024 + d0);
  float4* op = (float4*)(out + (size_t)row*1024 + d0);
  int j = inv[row];
  if (j < 0){ *op = xv; return; }
  int fr = b*2048 + j;
  float wgt = rw[fr];
  float4 hv = *(const float4*)(h + (size_t)fr*1024 + d0);
  uint2 yv = *(const uint2*)(y + (size_t)fr*1024 + d0);
  float y0=b2f((u16)(yv.x&0xffffu)), y1=b2f((u16)(yv.x>>16)), y2=b2f((u16)(yv.y&0xffffu)), y3=b2f((u16)(yv.y>>16));
  float4 ov;
  ov.x = xv.x + wgt*(hv.x + y0);
  ov.y = xv.y + wgt*(hv.y + y1);
  ov.z = xv.z + wgt*(hv.z + y2);
  ov.w = xv.w + wgt*(hv.w + y3);
  *op = ov;
}

extern "C" void kernel_launch(void* const* d_in, const int* in_sizes, int n_in,
                              void* d_out, int out_size, void* d_ws, size_t ws_size,
                              hipStream_t stream) {
  (void)in_sizes; (void)n_in; (void)out_size; (void)ws_size;
  const float* x     = (const float*)d_in[0];
  const float* fcos  = (const float*)d_in[2];
  const float* fsin  = (const float*)d_in[3];
  const float* wr    = (const float*)d_in[4];
  const float* anorm = (const float*)d_in[5];
  const float* wq    = (const float*)d_in[6];
  const float* wk    = (const float*)d_in[7];
  const float* wv    = (const float*)d_in[8];
  const float* wo    = (const float*)d_in[9];
  const float* fnorm = (const float*)d_in[10];
  const float* w1    = (const float*)d_in[11];
  const float* w2    = (const float*)d_in[12];
  const float* w3    = (const float*)d_in[13];
  float* out = (float*)d_out;

  char* W = (char*)d_ws;
  const size_t MB = 1024*1024;
  u16* WqkvT = (u16*)(W + 0);          // 6 MB  (3072 x 1024 bf16)
  u16* WoT   = (u16*)(W + 6*MB);       // 2 MB
  u16* W13T  = (u16*)(W + 8*MB);       // 16 MB (8192 x 1024, silu-interleaved)
  u16* W2T   = (u16*)(W + 24*MB);      // 8 MB  (1024 x 4096)
  u16* xn    = (u16*)(W + 32*MB);      // 8 MB  (dead after QKV gemm)
  u16* q_r   = (u16*)(W + 40*MB);      // 8 MB
  u16* k_r   = (u16*)(W + 48*MB);      // 8 MB
  u16* v_r   = (u16*)(W + 56*MB);      // 8 MB  (dead after v-transpose)
  u16* v_t   = (u16*)(W + 64*MB);      // 8 MB
  u16* attno = (u16*)(W + 72*MB);      // 8 MB  (dead after o-proj)
  float* hbuf= (float*)(W + 80*MB);    // 16 MB f32 (live till final)
  u16* hn    = (u16*)(W + 96*MB);      // 8 MB  (dead after FFN13)
  u16* g     = (u16*)(W + 104*MB);     // 32 MB
  u16* ybuf  = (u16*)(W + 32*MB);      // 8 MB overlay on dead xn
  float* logits = (float*)(W + 140*MB);            // 32 KB
  int*   sel    = (int*)(W + 140*MB + 64*1024);    // 16 KB
  float* rw     = (float*)(W + 140*MB + 96*1024);  // 16 KB
  int*   inv    = (int*)(W + 140*MB + 128*1024);   // 32 KB

  dim3 tb(32,8);
  transpose_f2b<<<dim3(32,32,1),  tb, 0, stream>>>(wq, WqkvT,                1024, 1024, 0);
  transpose_f2b<<<dim3(32,32,1),  tb, 0, stream>>>(wk, WqkvT + 1024*1024,    1024, 1024, 0);
  transpose_f2b<<<dim3(32,32,1),  tb, 0, stream>>>(wv, WqkvT + 2*1024*1024,  1024, 1024, 0);
  transpose_f2b<<<dim3(32,32,1),  tb, 0, stream>>>(wo, WoT,                  1024, 1024, 0);
  transpose_f2b<<<dim3(128,32,1), tb, 0, stream>>>(w1, W13T,                 1024, 4096, 1);
  transpose_f2b<<<dim3(128,32,1), tb, 0, stream>>>(w3, W13T,                 1024, 4096, 2);
  transpose_f2b<<<dim3(32,128,1), tb, 0, stream>>>(w2, W2T,                  4096, 1024, 0);

  router_kernel<<<2048, 256, 0, stream>>>(x, wr, logits);
  topk_kernel<<<2, 1024, 0, stream>>>(logits, sel, rw, inv);
  rmsnorm_kernel<<<4096, 256, 0, stream>>>(x, anorm, sel, xn);
  gemm_qkv<<<dim3(24,32), 256, 0, stream>>>(xn, WqkvT, fcos, fsin, q_r, k_r, v_r, 1024);
  transpose_bf16<<<dim3(2,64,32), tb, 0, stream>>>(v_r, v_t, 2048, 64);
  flash_kernel<<<dim3(16,32), 256, 0, stream>>>(q_r, k_r, v_t, attno);
  gemm_bt<64,float><<<dim3(16,32), 256, 0, stream>>>(attno, WoT, hbuf, x, sel, 4096, 1024, 1024);
  rmsnorm_kernel<<<4096, 256, 0, stream>>>(hbuf, fnorm, nullptr, hn);
  gemm13<<<dim3(64,32), 256, 0, stream>>>(hn, W13T, g, 1024);
  gemm_bt<64,u16><<<dim3(16,32), 256, 0, stream>>>(g, W2T, ybuf, nullptr, nullptr, 4096, 1024, 4096);
  final_kernel<<<8192, 256, 0, stream>>>(x, hbuf, ybuf, inv, rw, out);
}

// Round 5
// 526.485 us; speedup vs baseline: 1.0645x; 1.0645x over previous
//
#include <hip/hip_runtime.h>
#include <cstdint>
#include <cstddef>

typedef unsigned short u16;
typedef __bf16 bf16x8 __attribute__((ext_vector_type(8)));
typedef short s16x4 __attribute__((ext_vector_type(4)));
typedef float f32x4 __attribute__((ext_vector_type(4)));

// q is pre-scaled by 1/sqrt(64) * log2(e) so flash softmax runs in exp2 domain
#define SCALE_Q_LOG2E 0.18033688011112042f

static __device__ __forceinline__ float b2f(u16 u){ return __uint_as_float(((unsigned)u)<<16); }
static __device__ __forceinline__ u16 f2b(float f){
  unsigned u = __float_as_uint(f);
  return (u16)((u + 0x7fffu + ((u>>16)&1u)) >> 16);
}
// async global->LDS, 16 B per lane; LDS dest is wave-uniform base + lane*16
static __device__ __forceinline__ void gload_lds16(const void* g, void* l){
  auto gp = reinterpret_cast<__attribute__((address_space(1))) uint32_t*>(reinterpret_cast<uintptr_t>(g));
  auto lp = reinterpret_cast<__attribute__((address_space(3))) uint32_t*>(reinterpret_cast<uintptr_t>(l));
  __builtin_amdgcn_global_load_lds(gp, lp, 16, 0, 0);
}
// 16x16x16 bf16 MFMA (K=16): B-operand k-mapping (quad*4+j) matches C-layout rows,
// which lets flash feed P directly from the S^T accumulator registers.
static __device__ __forceinline__ f32x4 mfma16bf(s16x4 a, s16x4 b, f32x4 c){
#if __has_builtin(__builtin_amdgcn_mfma_f32_16x16x16bf16_1k)
  return __builtin_amdgcn_mfma_f32_16x16x16bf16_1k(a, b, c, 0, 0, 0);
#else
  f32x4 d = c;
  asm volatile("v_mfma_f32_16x16x16_bf16 %0, %1, %2, %0" : "+v"(d) : "v"(a), "v"(b));
  return d;
#endif
}

// ---------------- weight transpose f32 -> bf16, 32x32 tiles ----------------
// rowmap: 0 = identity; 1 = w1-interleave; 2 = w3-interleave
__global__ __launch_bounds__(256) void transpose_f2b(const float* __restrict__ in, u16* __restrict__ out,
                                                     int R, int C, int rowmap){
  __shared__ float tile[32][33];
  int tx = threadIdx.x, ty = threadIdx.y;
  int c0 = blockIdx.x*32, r0 = blockIdx.y*32;
  #pragma unroll
  for (int i=0;i<4;i++) tile[ty+i*8][tx] = in[(size_t)(r0+ty+i*8)*C + c0+tx];
  __syncthreads();
  #pragma unroll
  for (int i=0;i<4;i++){
    int c = c0+ty+i*8;
    int orow = c;
    if (rowmap==1) orow = (c>>4)*32 + (c&15);
    else if (rowmap==2) orow = (c>>4)*32 + 16 + (c&15);
    out[(size_t)orow*R + r0+tx] = f2b(tile[tx][ty+i*8]);
  }
}

// ---------------- bf16 raw transpose (for V), batched over z ----------------
__global__ __launch_bounds__(256) void transpose_bf16(const u16* __restrict__ in, u16* __restrict__ out,
                                                      int R, int C){
  __shared__ u16 tile[32][33];
  size_t zoff = (size_t)blockIdx.z * R * C;
  const u16* ip = in + zoff;
  u16* op = out + zoff;
  int tx = threadIdx.x, ty = threadIdx.y;
  int c0 = blockIdx.x*32, r0 = blockIdx.y*32;
  #pragma unroll
  for (int i=0;i<4;i++) tile[ty+i*8][tx] = ip[(size_t)(r0+ty+i*8)*C + c0+tx];
  __syncthreads();
  #pragma unroll
  for (int i=0;i<4;i++) op[(size_t)(c0+ty+i*8)*R + r0+tx] = tile[tx][ty+i*8];
}

// ---------------- router logits: one wave per row (f32) ----------------
__global__ __launch_bounds__(256) void router_kernel(const float* __restrict__ x, const float* __restrict__ wr,
                                                     float* __restrict__ logits){
  int row = blockIdx.x*4 + (threadIdx.x>>6);
  int l = threadIdx.x & 63;
  const float4* xr = (const float4*)(x + (size_t)row*1024) + l;
  const float4* wp = (const float4*)wr + l;
  float acc = 0.f;
  #pragma unroll
  for (int c=0;c<4;c++){
    float4 xv = xr[c*64];
    float4 wv = wp[c*64];
    acc += xv.x*wv.x + xv.y*wv.y + xv.z*wv.z + xv.w*wv.w;
  }
  #pragma unroll
  for (int m=1;m<64;m<<=1) acc += __shfl_xor(acc, m, 64);
  if (l==0) logits[row] = acc;
}

// ---------------- exact top-K (radix select) + softmax weights + inverse map ----------------
static __device__ __forceinline__ unsigned mapkey(float f){
  unsigned u = __float_as_uint(f);
  return (u & 0x80000000u) ? ~u : (u | 0x80000000u);
}
static __device__ unsigned blk_scan_excl(unsigned cnt, unsigned* swav){
  int t = threadIdx.x; int l = t&63, w = t>>6;
  unsigned v = cnt;
  #pragma unroll
  for (int off=1; off<64; off<<=1){
    unsigned n = __shfl_up(v, off, 64);
    if (l >= off) v += n;
  }
  __syncthreads();
  if (l==63) swav[w] = v;
  __syncthreads();
  if (t==0){ unsigned c=0; for (int i=0;i<16;i++){ unsigned tmp=swav[i]; swav[i]=c; c+=tmp; } }
  __syncthreads();
  return swav[w] + v - cnt;
}
__global__ __launch_bounds__(1024) void topk_kernel(const float* __restrict__ logits,
        int* __restrict__ sel, float* __restrict__ rw, int* __restrict__ inv){
  int b = blockIdx.x, t = threadIdx.x;
  int l = t&63, w = t>>6;
  __shared__ float vals[4096];
  __shared__ unsigned hist[256];
  __shared__ unsigned swav[16];
  __shared__ float fwav[16];
  __shared__ unsigned sh_prefix, sh_remaining;
  const float* lgp = logits + b*4096;
  for (int i=t;i<4096;i+=1024) vals[i]=lgp[i];
  if (t==0){ sh_prefix=0u; sh_remaining=2048u; }
  __syncthreads();
  for (int level=0; level<4; level++){
    int shift = 24 - level*8;
    if (t<256) hist[t]=0u;
    __syncthreads();
    unsigned pfx = sh_prefix;
    for (int i=t;i<4096;i+=1024){
      unsigned key = mapkey(vals[i]);
      if (level==0 || (key >> (shift+8)) == pfx)
        atomicAdd(&hist[(key>>shift)&255u], 1u);
    }
    __syncthreads();
    if (t==0){
      unsigned rem = sh_remaining, cum=0u; unsigned bsel=0u;
      for (int bin=255; bin>=0; bin--){
        unsigned hc = hist[bin];
        if (cum + hc >= rem){ bsel=(unsigned)bin; break; }
        cum += hc;
      }
      sh_remaining = rem - cum;
      sh_prefix = (pfx<<8) | bsel;
    }
    __syncthreads();
  }
  unsigned T = sh_prefix;
  unsigned req = sh_remaining;
  int i0 = t*4;
  unsigned gt_[4], eq_[4], fl_[4]; float v_[4];
  #pragma unroll
  for (int j=0;j<4;j++){
    v_[j] = vals[i0+j];
    unsigned key = mapkey(v_[j]);
    gt_[j] = key > T ? 1u:0u;
    eq_[j] = key == T ? 1u:0u;
  }
  unsigned eqbase = blk_scan_excl(eq_[0]+eq_[1]+eq_[2]+eq_[3], swav);
  unsigned er = eqbase;
  #pragma unroll
  for (int j=0;j<4;j++){ fl_[j] = gt_[j] | (eq_[j] & (er < req ? 1u:0u)); er += eq_[j]; }
  unsigned pbase = blk_scan_excl(fl_[0]+fl_[1]+fl_[2]+fl_[3], swav);
  unsigned p = pbase;
  #pragma unroll
  for (int j=0;j<4;j++){
    int i = i0+j;
    if (fl_[j]){ sel[b*2048+(int)p]=i; inv[b*4096+i]=(int)p; p++; }
    else inv[b*4096+i] = -1;
  }
  float mx = fmaxf(fmaxf(v_[0],v_[1]), fmaxf(v_[2],v_[3]));
  #pragma unroll
  for (int m=1;m<64;m<<=1) mx = fmaxf(mx, __shfl_xor(mx,m,64));
  __syncthreads();
  if (l==0) fwav[w]=mx;
  __syncthreads();
  if (t==0){ float g=fwav[0]; for(int i=1;i<16;i++) g=fmaxf(g,fwav[i]); fwav[0]=g; }
  __syncthreads();
  float gm = fwav[0];
  float zz = 0.f;
  #pragma unroll
  for (int j=0;j<4;j++) if (fl_[j]) zz += expf(v_[j]-gm);
  #pragma unroll
  for (int m=1;m<64;m<<=1) zz += __shfl_xor(zz,m,64);
  __syncthreads();
  if (l==0) fwav[w]=zz;
  __syncthreads();
  if (t==0){ float s=0.f; for(int i=0;i<16;i++) s+=fwav[i]; fwav[0]=s; }
  __syncthreads();
  float Z = fwav[0];
  unsigned p2 = pbase;
  #pragma unroll
  for (int j=0;j<4;j++) if (fl_[j]){ rw[b*2048+(int)p2] = expf(v_[j]-gm)/Z; p2++; }
}

// ---------------- (gathered) RMSNorm f32 -> bf16 ----------------
__global__ __launch_bounds__(256) void rmsnorm_kernel(const float* __restrict__ xin,
        const float* __restrict__ gamma, const int* __restrict__ sel,
        u16* __restrict__ xn){
  int r = blockIdx.x;
  int src = r;
  if (sel) src = (r>>11)*4096 + sel[r];
  const float* row = xin + (size_t)src*1024;
  int t = threadIdx.x, l = t&63, w = t>>6;
  int d0 = t*4;
  float4 xv = *(const float4*)(row + d0);
  float ss = xv.x*xv.x + xv.y*xv.y + xv.z*xv.z + xv.w*xv.w;
  #pragma unroll
  for (int m=1;m<64;m<<=1) ss += __shfl_xor(ss,m,64);
  __shared__ float red[4];
  if (l==0) red[w]=ss;
  __syncthreads();
  float tot = red[0]+red[1]+red[2]+red[3];
  float rms = rsqrtf(tot*(1.f/1024.f) + 1e-5f);
  float4 gv = *(const float4*)(gamma + d0);
  u16 o0=f2b(xv.x*rms*gv.x), o1=f2b(xv.y*rms*gv.y), o2=f2b(xv.z*rms*gv.z), o3=f2b(xv.w*rms*gv.w);
  uint2 ov; ov.x = (unsigned)o0 | ((unsigned)o1<<16); ov.y = (unsigned)o2 | ((unsigned)o3<<16);
  *(uint2*)(xn + (size_t)r*1024 + d0) = ov;
}

// ---------------- generic m97-style GEMM: C = A(128xK) * Bt(BNxK)^T (+resid/gather) ----------------
template<int BN, int BK, typename OT>
__global__ __launch_bounds__(256,2) void gemm_bt(const u16* __restrict__ A, const u16* __restrict__ Bt,
        OT* __restrict__ C, const float* __restrict__ resid, const int* __restrict__ sel,
        int M, int N, int Kd){
  __shared__ u16 As[128*BK];
  __shared__ u16 Bs[BN*BK];
  constexpr int NF = BN/32;
  constexpr int KK = BK/32;
  int t = threadIdx.x, w = t>>6, l = t&63, lg = l>>4, ln = l&15;
  int m0 = blockIdx.y*128, n0 = blockIdx.x*BN;
  int wm = (w&1)*64, wn = (w>>1)*(BN/2);
  f32x4 acc[4][NF] = {};
  for (int k0=0; k0<Kd; k0+=BK){
    __syncthreads();
    #pragma unroll
    for (int c=0;c<128*BK*2/4096;c++){
      int off = t*16 + c*4096;
      int row = off/(BK*2), ku = (off%(BK*2))>>1;
      gload_lds16(A + (size_t)(m0+row)*Kd + k0 + ku, &As[c*2048 + w*512]);
    }
    #pragma unroll
    for (int c=0;c<BN*BK*2/4096;c++){
      int off = t*16 + c*4096;
      int row = off/(BK*2), ku = (off%(BK*2))>>1;
      gload_lds16(Bt + (size_t)(n0+row)*Kd + k0 + ku, &Bs[c*2048 + w*512]);
    }
    __syncthreads();
    #pragma unroll
    for (int kk=0;kk<KK;kk++){
      bf16x8 af[4], bfv[NF];
      #pragma unroll
      for (int i=0;i<4;i++)  af[i]  = *(const bf16x8*)&As[(wm+i*16+ln)*BK + kk*32 + lg*8];
      #pragma unroll
      for (int i=0;i<NF;i++) bfv[i] = *(const bf16x8*)&Bs[(wn+i*16+ln)*BK + kk*32 + lg*8];
      #pragma unroll
      for (int mi=0;mi<4;mi++)
        #pragma unroll
        for (int ni=0;ni<NF;ni++)
          acc[mi][ni] = __builtin_amdgcn_mfma_f32_16x16x32_bf16(af[mi], bfv[ni], acc[mi][ni], 0,0,0);
    }
  }
  #pragma unroll
  for (int mi=0;mi<4;mi++){
    #pragma unroll
    for (int ni=0;ni<NF;ni++){
      #pragma unroll
      for (int r=0;r<4;r++){
        int row = m0+wm+mi*16+lg*4+r;
        int col = n0+wn+ni*16+ln;
        float v = acc[mi][ni][r];
        if (resid){
          size_t rrow = sel ? ((size_t)(row>>11)*4096 + sel[row]) : (size_t)row;
          v += resid[rrow*N + col];
        }
        if constexpr (sizeof(OT)==2) C[(size_t)row*N + col] = f2b(v);
        else                          C[(size_t)row*N + col] = v;
      }
    }
  }
}

// ---------------- FFN13 GEMM with fused SwiGLU epilogue ----------------
__global__ __launch_bounds__(256,2) void gemm13(const u16* __restrict__ A, const u16* __restrict__ Bt,
        u16* __restrict__ g, int Kd){
  __shared__ u16 As[128*32];
  __shared__ u16 Bs[128*32];
  int t = threadIdx.x, w = t>>6, l = t&63, lg = l>>4, ln = l&15;
  int m0 = blockIdx.y*128, n0 = blockIdx.x*128;
  int wm = (w&1)*64, wn = (w>>1)*64;
  f32x4 acc[4][4] = {};
  for (int k0=0; k0<Kd; k0+=32){
    __syncthreads();
    #pragma unroll
    for (int c=0;c<2;c++){
      int off = t*16 + c*4096;
      int row = off>>6, ku = (off&63)>>1;
      gload_lds16(A  + (size_t)(m0+row)*Kd + k0 + ku, &As[c*2048 + w*512]);
      gload_lds16(Bt + (size_t)(n0+row)*Kd + k0 + ku, &Bs[c*2048 + w*512]);
    }
    __syncthreads();
    bf16x8 af[4], bfv[4];
    #pragma unroll
    for (int i=0;i<4;i++){
      af[i]  = *(const bf16x8*)&As[(wm+i*16+ln)*32 + lg*8];
      bfv[i] = *(const bf16x8*)&Bs[(wn+i*16+ln)*32 + lg*8];
    }
    #pragma unroll
    for (int mi=0;mi<4;mi++)
      #pragma unroll
      for (int ni=0;ni<4;ni++)
        acc[mi][ni] = __builtin_amdgcn_mfma_f32_16x16x32_bf16(af[mi], bfv[ni], acc[mi][ni], 0,0,0);
  }
  int gbase = (n0+wn)>>1;
  #pragma unroll
  for (int mi=0;mi<4;mi++){
    #pragma unroll
    for (int p=0;p<2;p++){
      #pragma unroll
      for (int r=0;r<4;r++){
        int row = m0+wm+mi*16+lg*4+r;
        int col = gbase + p*16 + ln;
        float a1 = acc[mi][2*p][r], a3 = acc[mi][2*p+1][r];
        float s1 = a1 / (1.f + __expf(-a1));
        g[(size_t)row*4096 + col] = f2b(s1*a3);
      }
    }
  }
}

// ---------------- RoPE + QKV unpack (q scaled by 1/sqrt(HD)*log2e) ----------------
__global__ __launch_bounds__(256) void rope_kernel(const u16* __restrict__ QKV,
        const float* __restrict__ fcos, const float* __restrict__ fsin,
        u16* __restrict__ q_r, u16* __restrict__ k_r, u16* __restrict__ v_r){
  int row = blockIdx.x;              // b*2048+tok
  int tok = row & 2047;
  int t = threadIdx.x;
  int d0 = t*4;
  int h = d0 >> 6, wd = d0 & 63, i0 = wd >> 1;
  const u16* base = QKV + (size_t)row*3072;
  size_t ob = (((size_t)(row>>11)*16 + h)*2048 + (size_t)tok)*64 + wd;
  float c0 = fcos[tok*32+i0],   s0 = fsin[tok*32+i0];
  float c1 = fcos[tok*32+i0+1], s1 = fsin[tok*32+i0+1];
  const u16* qp = base + d0;
  float x0=b2f(qp[0]), x1=b2f(qp[1]), x2=b2f(qp[2]), x3=b2f(qp[3]);
  q_r[ob]   = f2b((x0*c0-x1*s0)*SCALE_Q_LOG2E);
  q_r[ob+1] = f2b((x0*s0+x1*c0)*SCALE_Q_LOG2E);
  q_r[ob+2] = f2b((x2*c1-x3*s1)*SCALE_Q_LOG2E);
  q_r[ob+3] = f2b((x2*s1+x3*c1)*SCALE_Q_LOG2E);
  const u16* kp = base + 1024 + d0;
  x0=b2f(kp[0]); x1=b2f(kp[1]); x2=b2f(kp[2]); x3=b2f(kp[3]);
  k_r[ob]   = f2b(x0*c0-x1*s0);
  k_r[ob+1] = f2b(x0*s0+x1*c0);
  k_r[ob+2] = f2b(x2*c1-x3*s1);
  k_r[ob+3] = f2b(x2*s1+x3*c1);
  const u16* vp = base + 2048 + d0;
  v_r[ob]=vp[0]; v_r[ob+1]=vp[1]; v_r[ob+2]=vp[2]; v_r[ob+3]=vp[3];
}

// ---------------- flash attention, causal, HD=64, S^T formulation ----------------
// S^T = K Q^T  -> P^T in C-layout (q=ln, kv=lg*4+r) == B-operand layout of 16x16x16 MFMA.
// PV: O^T[d][q] += V_frag * P^T_frag with P straight from registers (no LDS round-trip).
// Row stats reduce over lg only: 2 shfl steps; mi/li/alpha are per-lane scalars.
__global__ __launch_bounds__(256,2) void flash_kernel(const u16* __restrict__ q_r,
        const u16* __restrict__ k_r, const u16* __restrict__ v_t, u16* __restrict__ o){
  const int S = 2048;
  int pr = blockIdx.x, bh = blockIdx.y;
  int b = bh>>4, h = bh&15;
  int t = threadIdx.x, w = t>>6, l = t&63, lg = l>>4, ln = l&15;
  __shared__ u16 Ks[2][64*72];   // [token][dim]
  __shared__ u16 Vs[2][64*72];   // [dim][token]
  const u16* qb = q_r + (size_t)bh*S*64;
  const u16* kb = k_r + (size_t)bh*S*64;
  const u16* vb = v_t + (size_t)bh*64*S;
  int rr = t>>2, p16 = (t&3)*16;
  #pragma unroll
  for (int ti=0; ti<2; ti++){
    int qt = ti ? (31-pr) : pr;
    int q0 = qt*64;
    int q = q0 + w*16 + ln;      // this lane's q row
    bf16x8 qf0 = *(const bf16x8*)(qb + (size_t)q*64 + lg*8);
    bf16x8 qf1 = *(const bf16x8*)(qb + (size_t)q*64 + 32 + lg*8);
    f32x4 oaccT[4] = {};         // O^T: col q=ln, row d = dt*16+lg*4+r
    float mi = -1e30f, li = 0.f;
    __syncthreads();
    {
      *(bf16x8*)&Ks[0][rr*72+p16]   = *(const bf16x8*)(kb + (size_t)rr*64 + p16);
      *(bf16x8*)&Ks[0][rr*72+p16+8] = *(const bf16x8*)(kb + (size_t)rr*64 + p16 + 8);
      *(bf16x8*)&Vs[0][rr*72+p16]   = *(const bf16x8*)(vb + (size_t)rr*S + p16);
      *(bf16x8*)&Vs[0][rr*72+p16+8] = *(const bf16x8*)(vb + (size_t)rr*S + p16 + 8);
    }
    __syncthreads();
    for (int kv=0; kv<=qt; kv++){
      int cur = kv&1;
      int k0 = kv*64;
      bool hasnext = kv < qt;
      bf16x8 nk0, nk1, nv0, nv1;
      if (hasnext){
        int kn = k0 + 64;
        nk0 = *(const bf16x8*)(kb + (size_t)(kn+rr)*64 + p16);
        nk1 = *(const bf16x8*)(kb + (size_t)(kn+rr)*64 + p16 + 8);
        nv0 = *(const bf16x8*)(vb + (size_t)rr*S + kn + p16);
        nv1 = *(const bf16x8*)(vb + (size_t)rr*S + kn + p16 + 8);
      }
      // S^T chunks: D[kv_local=lg*4+r][q=ln]
      f32x4 sv[4];
      #pragma unroll
      for (int ni=0;ni<4;ni++){
        bf16x8 kf0 = *(const bf16x8*)&Ks[cur][(ni*16+ln)*72 + lg*8];
        bf16x8 kf1 = *(const bf16x8*)&Ks[cur][(ni*16+ln)*72 + 32 + lg*8];
        f32x4 z = {};
        z = __builtin_amdgcn_mfma_f32_16x16x32_bf16(kf0, qf0, z, 0,0,0);
        z = __builtin_amdgcn_mfma_f32_16x16x32_bf16(kf1, qf1, z, 0,0,0);
        sv[ni] = z;
      }
      bool diag = (kv==qt);
      float rm = -1e30f;
      if (diag){
        #pragma unroll
        for (int ni=0;ni<4;ni++)
          #pragma unroll
          for (int r=0;r<4;r++){
            float xs = sv[ni][r];
            if (k0+ni*16+lg*4+r > q) xs = -1e30f;
            sv[ni][r] = xs;
            rm = fmaxf(rm, xs);
          }
      } else {
        #pragma unroll
        for (int ni=0;ni<4;ni++)
          #pragma unroll
          for (int r=0;r<4;r++) rm = fmaxf(rm, sv[ni][r]);
      }
      rm = fmaxf(rm, __shfl_xor(rm, 16, 64));
      rm = fmaxf(rm, __shfl_xor(rm, 32, 64));
      float mn = fmaxf(mi, rm);
      float alpha = exp2f(mi - mn);
      float ls = 0.f;
      s16x4 pf[4];
      #pragma unroll
      for (int ni=0;ni<4;ni++){
        float p0 = exp2f(sv[ni][0]-mn);
        float p1 = exp2f(sv[ni][1]-mn);
        float p2 = exp2f(sv[ni][2]-mn);
        float p3 = exp2f(sv[ni][3]-mn);
        ls += (p0+p1)+(p2+p3);
        s16x4 pp;
        pp[0]=(short)f2b(p0); pp[1]=(short)f2b(p1); pp[2]=(short)f2b(p2); pp[3]=(short)f2b(p3);
        pf[ni]=pp;
      }
      ls += __shfl_xor(ls, 16, 64);
      ls += __shfl_xor(ls, 32, 64);
      li = li*alpha + ls;
      mi = mn;
      // PV: O^T[d=dt*16+lg*4+r][q=ln] += V[kv][d] * P^T[kv][q]
      #pragma unroll
      for (int dt=0; dt<4; dt++){
        f32x4 oo = oaccT[dt];
        oo[0]*=alpha; oo[1]*=alpha; oo[2]*=alpha; oo[3]*=alpha;
        #pragma unroll
        for (int ni=0;ni<4;ni++){
          s16x4 vf = *(const s16x4*)&Vs[cur][(dt*16+ln)*72 + ni*16 + lg*4];
          oo = mfma16bf(vf, pf[ni], oo);
        }
        oaccT[dt] = oo;
      }
      if (hasnext){
        int nb = cur^1;
        *(bf16x8*)&Ks[nb][rr*72+p16]   = nk0;
        *(bf16x8*)&Ks[nb][rr*72+p16+8] = nk1;
        *(bf16x8*)&Vs[nb][rr*72+p16]   = nv0;
        *(bf16x8*)&Vs[nb][rr*72+p16+8] = nv1;
      }
      __syncthreads();
    }
    // epilogue: lane writes 4 consecutive dims for its token
    {
      int tok = q0 + w*16 + ln;
      u16* ob = o + ((size_t)(b*S+tok))*1024 + h*64 + lg*4;
      #pragma unroll
      for (int dt=0; dt<4; dt++){
        u16 a0=f2b(oaccT[dt][0]/li), a1=f2b(oaccT[dt][1]/li);
        u16 a2=f2b(oaccT[dt][2]/li), a3=f2b(oaccT[dt][3]/li);
        uint2 pv; pv.x = (unsigned)a0 | ((unsigned)a1<<16); pv.y = (unsigned)a2 | ((unsigned)a3<<16);
        *(uint2*)(ob + dt*16) = pv;
      }
    }
  }
}

// ---------------- out = x (+ rw * (h + y) on selected rows), f32 out ----------------
__global__ __launch_bounds__(256) void final_kernel(const float* __restrict__ x, const float* __restrict__ h,
        const u16* __restrict__ y, const int* __restrict__ inv, const float* __restrict__ rw,
        float* __restrict__ out){
  int row = blockIdx.x;
  int b = row>>12;
  int t = threadIdx.x, d0 = t*4;
  float4 xv = *(const float4*)(x + (size_t)row*1024 + d0);
  float4* op = (float4*)(out + (size_t)row*1024 + d0);
  int j = inv[row];
  if (j < 0){ *op = xv; return; }
  int fr = b*2048 + j;
  float wgt = rw[fr];
  float4 hv = *(const float4*)(h + (size_t)fr*1024 + d0);
  uint2 yv = *(const uint2*)(y + (size_t)fr*1024 + d0);
  float y0=b2f((u16)(yv.x&0xffffu)), y1=b2f((u16)(yv.x>>16)), y2=b2f((u16)(yv.y&0xffffu)), y3=b2f((u16)(yv.y>>16));
  float4 ov;
  ov.x = xv.x + wgt*(hv.x + y0);
  ov.y = xv.y + wgt*(hv.y + y1);
  ov.z = xv.z + wgt*(hv.z + y2);
  ov.w = xv.w + wgt*(hv.w + y3);
  *op = ov;
}

extern "C" void kernel_launch(void* const* d_in, const int* in_sizes, int n_in,
                              void* d_out, int out_size, void* d_ws, size_t ws_size,
                              hipStream_t stream) {
  (void)in_sizes; (void)n_in; (void)out_size; (void)ws_size;
  const float* x     = (const float*)d_in[0];
  const float* fcos  = (const float*)d_in[2];
  const float* fsin  = (const float*)d_in[3];
  const float* wr    = (const float*)d_in[4];
  const float* anorm = (const float*)d_in[5];
  const float* wq    = (const float*)d_in[6];
  const float* wk    = (const float*)d_in[7];
  const float* wv    = (const float*)d_in[8];
  const float* wo    = (const float*)d_in[9];
  const float* fnorm = (const float*)d_in[10];
  const float* w1    = (const float*)d_in[11];
  const float* w2    = (const float*)d_in[12];
  const float* w3    = (const float*)d_in[13];
  float* out = (float*)d_out;

  char* W = (char*)d_ws;
  const size_t MB = 1024*1024;
  u16* WqkvT = (u16*)(W + 0);          // 6 MB
  u16* WoT   = (u16*)(W + 6*MB);       // 2 MB
  u16* W13T  = (u16*)(W + 8*MB);       // 16 MB (silu-interleaved)
  u16* W2T   = (u16*)(W + 24*MB);      // 8 MB
  u16* xn    = (u16*)(W + 32*MB);      // 8 MB  (dead after QKV gemm)
  u16* QKV   = (u16*)(W + 40*MB);      // 24 MB (dead after rope)
  u16* q_r   = (u16*)(W + 64*MB);      // 8 MB
  u16* k_r   = (u16*)(W + 72*MB);      // 8 MB
  u16* v_r   = (u16*)(W + 80*MB);      // 8 MB  (dead after v-transpose)
  u16* v_t   = (u16*)(W + 88*MB);      // 8 MB
  u16* attno = (u16*)(W + 96*MB);      // 8 MB  (dead after o-proj)
  float* hbuf= (float*)(W + 104*MB);   // 16 MB f32 (live till final)
  u16* hn    = (u16*)(W + 120*MB);     // 8 MB  (dead after FFN13)
  u16* g     = (u16*)(W + 128*MB);     // 32 MB
  u16* ybuf  = (u16*)(W + 32*MB);      // 8 MB overlay on dead xn
  float* logits = (float*)(W + 160*MB);            // 32 KB
  int*   sel    = (int*)(W + 160*MB + 64*1024);    // 16 KB
  float* rw     = (float*)(W + 160*MB + 96*1024);  // 16 KB
  int*   inv    = (int*)(W + 160*MB + 128*1024);   // 32 KB

  dim3 tb(32,8);
  transpose_f2b<<<dim3(32,32,1),  tb, 0, stream>>>(wq, WqkvT,                1024, 1024, 0);
  transpose_f2b<<<dim3(32,32,1),  tb, 0, stream>>>(wk, WqkvT + 1024*1024,    1024, 1024, 0);
  transpose_f2b<<<dim3(32,32,1),  tb, 0, stream>>>(wv, WqkvT + 2*1024*1024,  1024, 1024, 0);
  transpose_f2b<<<dim3(32,32,1),  tb, 0, stream>>>(wo, WoT,                  1024, 1024, 0);
  transpose_f2b<<<dim3(128,32,1), tb, 0, stream>>>(w1, W13T,                 1024, 4096, 1);
  transpose_f2b<<<dim3(128,32,1), tb, 0, stream>>>(w3, W13T,                 1024, 4096, 2);
  transpose_f2b<<<dim3(32,128,1), tb, 0, stream>>>(w2, W2T,                  4096, 1024, 0);

  router_kernel<<<2048, 256, 0, stream>>>(x, wr, logits);
  topk_kernel<<<2, 1024, 0, stream>>>(logits, sel, rw, inv);
  rmsnorm_kernel<<<4096, 256, 0, stream>>>(x, anorm, sel, xn);
  gemm_bt<128,32,u16><<<dim3(24,32), 256, 0, stream>>>(xn, WqkvT, QKV, nullptr, nullptr, 4096, 3072, 1024);
  rope_kernel<<<4096, 256, 0, stream>>>(QKV, fcos, fsin, q_r, k_r, v_r);
  transpose_bf16<<<dim3(2,64,32), tb, 0, stream>>>(v_r, v_t, 2048, 64);
  flash_kernel<<<dim3(16,32), 256, 0, stream>>>(q_r, k_r, v_t, attno);
  gemm_bt<64,32,float><<<dim3(16,32), 256, 0, stream>>>(attno, WoT, hbuf, x, sel, 4096, 1024, 1024);
  rmsnorm_kernel<<<4096, 256, 0, stream>>>(hbuf, fnorm, nullptr, hn);
  gemm13<<<dim3(64,32), 256, 0, stream>>>(hn, W13T, g, 1024);
  gemm_bt<64,64,u16><<<dim3(16,32), 256, 0, stream>>>(g, W2T, ybuf, nullptr, nullptr, 4096, 1024, 4096);
  final_kernel<<<8192, 256, 0, stream>>>(x, hbuf, ybuf, inv, rw, out);
}

// Round 6
// 489.447 us; speedup vs baseline: 1.1451x; 1.0757x over previous
//
#include <hip/hip_runtime.h>
#include <cstdint>
#include <cstddef>

typedef unsigned short u16;
typedef __bf16 bf16x8 __attribute__((ext_vector_type(8)));
typedef short s16x4 __attribute__((ext_vector_type(4)));
typedef float f32x4 __attribute__((ext_vector_type(4)));

// q is pre-scaled by 1/sqrt(64) * log2(e) so flash softmax runs in exp2 domain
#define SCALE_Q_LOG2E 0.18033688011112042f

static __device__ __forceinline__ float b2f(u16 u){ return __uint_as_float(((unsigned)u)<<16); }
static __device__ __forceinline__ u16 f2b(float f){
  unsigned u = __float_as_uint(f);
  return (u16)((u + 0x7fffu + ((u>>16)&1u)) >> 16);
}
// async global->LDS, 16 B per lane; LDS dest is wave-uniform base + lane*16
static __device__ __forceinline__ void gload_lds16(const void* g, void* l){
  auto gp = reinterpret_cast<__attribute__((address_space(1))) uint32_t*>(reinterpret_cast<uintptr_t>(g));
  auto lp = reinterpret_cast<__attribute__((address_space(3))) uint32_t*>(reinterpret_cast<uintptr_t>(l));
  __builtin_amdgcn_global_load_lds(gp, lp, 16, 0, 0);
}
// 16x16x16 bf16 MFMA (K=16): B-operand k-mapping matches C-layout rows -> P from registers
static __device__ __forceinline__ f32x4 mfma16bf(s16x4 a, s16x4 b, f32x4 c){
#if __has_builtin(__builtin_amdgcn_mfma_f32_16x16x16bf16_1k)
  return __builtin_amdgcn_mfma_f32_16x16x16bf16_1k(a, b, c, 0, 0, 0);
#else
  f32x4 d = c;
  asm volatile("v_mfma_f32_16x16x16_bf16 %0, %1, %2, %0" : "+v"(d) : "v"(a), "v"(b));
  return d;
#endif
}

// ---------------- batched weight prep: all 7 transposes (f32->bf16) in ONE launch ----------------
// rowmap: 0 identity; 1 w1-interleave; 2 w3-interleave (for fused-SwiGLU W13T layout)
__global__ __launch_bounds__(256) void prep_weights(
    const float* __restrict__ wq, const float* __restrict__ wk,
    const float* __restrict__ wv, const float* __restrict__ wo,
    const float* __restrict__ w1, const float* __restrict__ w3,
    const float* __restrict__ w2,
    u16* __restrict__ WqkvT, u16* __restrict__ WoT,
    u16* __restrict__ W13T, u16* __restrict__ W2T){
  __shared__ float tile[32][33];
  int bx = blockIdx.x;
  const float* in; u16* out; int R, C, rowmap, tcol, trow;
  if (bx < 4096){
    int wsel = bx>>10, tid = bx&1023;
    in = (wsel==0)?wq:(wsel==1)?wk:(wsel==2)?wv:wo;
    out = (wsel<3) ? (WqkvT + (size_t)wsel*1024*1024) : WoT;
    R=1024; C=1024; rowmap=0; tcol=tid&31; trow=tid>>5;
  } else if (bx < 12288){
    int wsel=(bx-4096)>>12, tid=(bx-4096)&4095;
    in = wsel ? w3 : w1; out = W13T; R=1024; C=4096; rowmap=1+wsel;
    tcol=tid&127; trow=tid>>7;
  } else {
    int tid = bx-12288;
    in = w2; out = W2T; R=4096; C=1024; rowmap=0;
    tcol=tid&31; trow=tid>>5;
  }
  int t=threadIdx.x, tx=t&31, ty=t>>5;
  int c0=tcol*32, r0=trow*32;
  #pragma unroll
  for (int i=0;i<4;i++) tile[ty+i*8][tx] = in[(size_t)(r0+ty+i*8)*C + c0+tx];
  __syncthreads();
  #pragma unroll
  for (int i=0;i<4;i++){
    int c = c0+ty+i*8;
    int orow = c;
    if (rowmap==1) orow = (c>>4)*32 + (c&15);
    else if (rowmap==2) orow = (c>>4)*32 + 16 + (c&15);
    out[(size_t)orow*R + r0+tx] = f2b(tile[tx][ty+i*8]);
  }
}

// ---------------- bf16 raw transpose (for V), batched over z ----------------
__global__ __launch_bounds__(256) void transpose_bf16(const u16* __restrict__ in, u16* __restrict__ out,
                                                      int R, int C){
  __shared__ u16 tile[32][33];
  size_t zoff = (size_t)blockIdx.z * R * C;
  const u16* ip = in + zoff;
  u16* op = out + zoff;
  int tx = threadIdx.x, ty = threadIdx.y;
  int c0 = blockIdx.x*32, r0 = blockIdx.y*32;
  #pragma unroll
  for (int i=0;i<4;i++) tile[ty+i*8][tx] = ip[(size_t)(r0+ty+i*8)*C + c0+tx];
  __syncthreads();
  #pragma unroll
  for (int i=0;i<4;i++) op[(size_t)(c0+ty+i*8)*R + r0+tx] = tile[tx][ty+i*8];
}

// ---------------- router logits: one wave per row (f32) ----------------
__global__ __launch_bounds__(256) void router_kernel(const float* __restrict__ x, const float* __restrict__ wr,
                                                     float* __restrict__ logits){
  int row = blockIdx.x*4 + (threadIdx.x>>6);
  int l = threadIdx.x & 63;
  const float4* xr = (const float4*)(x + (size_t)row*1024) + l;
  const float4* wp = (const float4*)wr + l;
  float acc = 0.f;
  #pragma unroll
  for (int c=0;c<4;c++){
    float4 xv = xr[c*64];
    float4 wv = wp[c*64];
    acc += xv.x*wv.x + xv.y*wv.y + xv.z*wv.z + xv.w*wv.w;
  }
  #pragma unroll
  for (int m=1;m<64;m<<=1) acc += __shfl_xor(acc, m, 64);
  if (l==0) logits[row] = acc;
}

// ---------------- exact top-K (radix select) + softmax weights + inverse map ----------------
static __device__ __forceinline__ unsigned mapkey(float f){
  unsigned u = __float_as_uint(f);
  return (u & 0x80000000u) ? ~u : (u | 0x80000000u);
}
static __device__ unsigned blk_scan_excl(unsigned cnt, unsigned* swav){
  int t = threadIdx.x; int l = t&63, w = t>>6;
  unsigned v = cnt;
  #pragma unroll
  for (int off=1; off<64; off<<=1){
    unsigned n = __shfl_up(v, off, 64);
    if (l >= off) v += n;
  }
  __syncthreads();
  if (l==63) swav[w] = v;
  __syncthreads();
  if (t==0){ unsigned c=0; for (int i=0;i<16;i++){ unsigned tmp=swav[i]; swav[i]=c; c+=tmp; } }
  __syncthreads();
  return swav[w] + v - cnt;
}
__global__ __launch_bounds__(1024) void topk_kernel(const float* __restrict__ logits,
        int* __restrict__ sel, float* __restrict__ rw, int* __restrict__ inv){
  int b = blockIdx.x, t = threadIdx.x;
  int l = t&63, w = t>>6;
  __shared__ float vals[4096];
  __shared__ unsigned hist[256];
  __shared__ unsigned swav[16];
  __shared__ float fwav[16];
  __shared__ unsigned sh_prefix, sh_remaining;
  const float* lgp = logits + b*4096;
  for (int i=t;i<4096;i+=1024) vals[i]=lgp[i];
  if (t==0){ sh_prefix=0u; sh_remaining=2048u; }
  __syncthreads();
  for (int level=0; level<4; level++){
    int shift = 24 - level*8;
    if (t<256) hist[t]=0u;
    __syncthreads();
    unsigned pfx = sh_prefix;
    for (int i=t;i<4096;i+=1024){
      unsigned key = mapkey(vals[i]);
      if (level==0 || (key >> (shift+8)) == pfx)
        atomicAdd(&hist[(key>>shift)&255u], 1u);
    }
    __syncthreads();
    if (t==0){
      unsigned rem = sh_remaining, cum=0u; unsigned bsel=0u;
      for (int bin=255; bin>=0; bin--){
        unsigned hc = hist[bin];
        if (cum + hc >= rem){ bsel=(unsigned)bin; break; }
        cum += hc;
      }
      sh_remaining = rem - cum;
      sh_prefix = (pfx<<8) | bsel;
    }
    __syncthreads();
  }
  unsigned T = sh_prefix;
  unsigned req = sh_remaining;
  int i0 = t*4;
  unsigned gt_[4], eq_[4], fl_[4]; float v_[4];
  #pragma unroll
  for (int j=0;j<4;j++){
    v_[j] = vals[i0+j];
    unsigned key = mapkey(v_[j]);
    gt_[j] = key > T ? 1u:0u;
    eq_[j] = key == T ? 1u:0u;
  }
  unsigned eqbase = blk_scan_excl(eq_[0]+eq_[1]+eq_[2]+eq_[3], swav);
  unsigned er = eqbase;
  #pragma unroll
  for (int j=0;j<4;j++){ fl_[j] = gt_[j] | (eq_[j] & (er < req ? 1u:0u)); er += eq_[j]; }
  unsigned pbase = blk_scan_excl(fl_[0]+fl_[1]+fl_[2]+fl_[3], swav);
  unsigned p = pbase;
  #pragma unroll
  for (int j=0;j<4;j++){
    int i = i0+j;
    if (fl_[j]){ sel[b*2048+(int)p]=i; inv[b*4096+i]=(int)p; p++; }
    else inv[b*4096+i] = -1;
  }
  float mx = fmaxf(fmaxf(v_[0],v_[1]), fmaxf(v_[2],v_[3]));
  #pragma unroll
  for (int m=1;m<64;m<<=1) mx = fmaxf(mx, __shfl_xor(mx,m,64));
  __syncthreads();
  if (l==0) fwav[w]=mx;
  __syncthreads();
  if (t==0){ float g=fwav[0]; for(int i=1;i<16;i++) g=fmaxf(g,fwav[i]); fwav[0]=g; }
  __syncthreads();
  float gm = fwav[0];
  float zz = 0.f;
  #pragma unroll
  for (int j=0;j<4;j++) if (fl_[j]) zz += expf(v_[j]-gm);
  #pragma unroll
  for (int m=1;m<64;m<<=1) zz += __shfl_xor(zz,m,64);
  __syncthreads();
  if (l==0) fwav[w]=zz;
  __syncthreads();
  if (t==0){ float s=0.f; for(int i=0;i<16;i++) s+=fwav[i]; fwav[0]=s; }
  __syncthreads();
  float Z = fwav[0];
  unsigned p2 = pbase;
  #pragma unroll
  for (int j=0;j<4;j++) if (fl_[j]){ rw[b*2048+(int)p2] = expf(v_[j]-gm)/Z; p2++; }
}

// ---------------- (gathered) RMSNorm f32 -> bf16 ----------------
__global__ __launch_bounds__(256) void rmsnorm_kernel(const float* __restrict__ xin,
        const float* __restrict__ gamma, const int* __restrict__ sel,
        u16* __restrict__ xn){
  int r = blockIdx.x;
  int src = r;
  if (sel) src = (r>>11)*4096 + sel[r];
  const float* row = xin + (size_t)src*1024;
  int t = threadIdx.x, l = t&63, w = t>>6;
  int d0 = t*4;
  float4 xv = *(const float4*)(row + d0);
  float ss = xv.x*xv.x + xv.y*xv.y + xv.z*xv.z + xv.w*xv.w;
  #pragma unroll
  for (int m=1;m<64;m<<=1) ss += __shfl_xor(ss,m,64);
  __shared__ float red[4];
  if (l==0) red[w]=ss;
  __syncthreads();
  float tot = red[0]+red[1]+red[2]+red[3];
  float rms = rsqrtf(tot*(1.f/1024.f) + 1e-5f);
  float4 gv = *(const float4*)(gamma + d0);
  u16 o0=f2b(xv.x*rms*gv.x), o1=f2b(xv.y*rms*gv.y), o2=f2b(xv.z*rms*gv.z), o3=f2b(xv.w*rms*gv.w);
  uint2 ov; ov.x = (unsigned)o0 | ((unsigned)o1<<16); ov.y = (unsigned)o2 | ((unsigned)o3<<16);
  *(uint2*)(xn + (size_t)r*1024 + d0) = ov;
}

// XOR-swizzle of 16B k-blocks within an LDS row: kills the 8/16-way bank conflicts
// of the power-of-2 row stride while keeping global_load_lds lane-contiguous dests.
template<int BK>
static __device__ __forceinline__ int swz(int row, int blk){
  if constexpr (BK==64) return blk ^ (row&7);
  else                  return blk ^ ((row>>1)&3);
}

// ---------------- generic m97-style GEMM: C = A(128xK) * Bt(BNxK)^T (+resid/gather) ----------------
template<int BN, int BK, typename OT>
__global__ __launch_bounds__(256,2) void gemm_bt(const u16* __restrict__ A, const u16* __restrict__ Bt,
        OT* __restrict__ C, const float* __restrict__ resid, const int* __restrict__ sel,
        int M, int N, int Kd){
  __shared__ u16 As[128*BK];
  __shared__ u16 Bs[BN*BK];
  constexpr int NF = BN/32;
  constexpr int KK = BK/32;
  int t = threadIdx.x, w = t>>6, l = t&63, lg = l>>4, ln = l&15;
  int m0 = blockIdx.y*128, n0 = blockIdx.x*BN;
  int wm = (w&1)*64, wn = (w>>1)*(BN/2);
  f32x4 acc[4][NF] = {};
  for (int k0=0; k0<Kd; k0+=BK){
    __syncthreads();
    #pragma unroll
    for (int c=0;c<128*BK*2/4096;c++){
      int off = t*16 + c*4096;
      int row = off/(BK*2), pb = (off%(BK*2))>>4;
      gload_lds16(A + (size_t)(m0+row)*Kd + k0 + swz<BK>(row,pb)*8, &As[c*2048 + w*512]);
    }
    #pragma unroll
    for (int c=0;c<BN*BK*2/4096;c++){
      int off = t*16 + c*4096;
      int row = off/(BK*2), pb = (off%(BK*2))>>4;
      gload_lds16(Bt + (size_t)(n0+row)*Kd + k0 + swz<BK>(row,pb)*8, &Bs[c*2048 + w*512]);
    }
    __syncthreads();
    #pragma unroll
    for (int kk=0;kk<KK;kk++){
      bf16x8 af[4], bfv[NF];
      #pragma unroll
      for (int i=0;i<4;i++){
        int r = wm+i*16+ln;
        af[i] = *(const bf16x8*)&As[r*BK + swz<BK>(r, kk*4+lg)*8];
      }
      #pragma unroll
      for (int i=0;i<NF;i++){
        int r = wn+i*16+ln;
        bfv[i] = *(const bf16x8*)&Bs[r*BK + swz<BK>(r, kk*4+lg)*8];
      }
      #pragma unroll
      for (int mi=0;mi<4;mi++)
        #pragma unroll
        for (int ni=0;ni<NF;ni++)
          acc[mi][ni] = __builtin_amdgcn_mfma_f32_16x16x32_bf16(af[mi], bfv[ni], acc[mi][ni], 0,0,0);
    }
  }
  #pragma unroll
  for (int mi=0;mi<4;mi++){
    #pragma unroll
    for (int ni=0;ni<NF;ni++){
      #pragma unroll
      for (int r=0;r<4;r++){
        int row = m0+wm+mi*16+lg*4+r;
        int col = n0+wn+ni*16+ln;
        float v = acc[mi][ni][r];
        if (resid){
          size_t rrow = sel ? ((size_t)(row>>11)*4096 + sel[row]) : (size_t)row;
          v += resid[rrow*N + col];
        }
        if constexpr (sizeof(OT)==2) C[(size_t)row*N + col] = f2b(v);
        else                          C[(size_t)row*N + col] = v;
      }
    }
  }
}

// ---------------- FFN13 GEMM with fused SwiGLU epilogue (BK=64, swizzled) ----------------
__global__ __launch_bounds__(256,2) void gemm13(const u16* __restrict__ A, const u16* __restrict__ Bt,
        u16* __restrict__ g, int Kd){
  constexpr int BK = 64;
  __shared__ u16 As[128*BK];
  __shared__ u16 Bs[128*BK];
  int t = threadIdx.x, w = t>>6, l = t&63, lg = l>>4, ln = l&15;
  int m0 = blockIdx.y*128, n0 = blockIdx.x*128;
  int wm = (w&1)*64, wn = (w>>1)*64;
  f32x4 acc[4][4] = {};
  for (int k0=0; k0<Kd; k0+=BK){
    __syncthreads();
    #pragma unroll
    for (int c=0;c<4;c++){
      int off = t*16 + c*4096;
      int row = off/(BK*2), pb = (off%(BK*2))>>4;
      gload_lds16(A  + (size_t)(m0+row)*Kd + k0 + swz<BK>(row,pb)*8, &As[c*2048 + w*512]);
      gload_lds16(Bt + (size_t)(n0+row)*Kd + k0 + swz<BK>(row,pb)*8, &Bs[c*2048 + w*512]);
    }
    __syncthreads();
    #pragma unroll
    for (int kk=0;kk<2;kk++){
      bf16x8 af[4], bfv[4];
      #pragma unroll
      for (int i=0;i<4;i++){
        int ra = wm+i*16+ln, rb = wn+i*16+ln;
        af[i]  = *(const bf16x8*)&As[ra*BK + swz<BK>(ra, kk*4+lg)*8];
        bfv[i] = *(const bf16x8*)&Bs[rb*BK + swz<BK>(rb, kk*4+lg)*8];
      }
      #pragma unroll
      for (int mi=0;mi<4;mi++)
        #pragma unroll
        for (int ni=0;ni<4;ni++)
          acc[mi][ni] = __builtin_amdgcn_mfma_f32_16x16x32_bf16(af[mi], bfv[ni], acc[mi][ni], 0,0,0);
    }
  }
  int gbase = (n0+wn)>>1;
  #pragma unroll
  for (int mi=0;mi<4;mi++){
    #pragma unroll
    for (int p=0;p<2;p++){
      #pragma unroll
      for (int r=0;r<4;r++){
        int row = m0+wm+mi*16+lg*4+r;
        int col = gbase + p*16 + ln;
        float a1 = acc[mi][2*p][r], a3 = acc[mi][2*p+1][r];
        float s1 = a1 / (1.f + __expf(-a1));
        g[(size_t)row*4096 + col] = f2b(s1*a3);
      }
    }
  }
}

// ---------------- RoPE + QKV unpack (q scaled by 1/sqrt(HD)*log2e) ----------------
__global__ __launch_bounds__(256) void rope_kernel(const u16* __restrict__ QKV,
        const float* __restrict__ fcos, const float* __restrict__ fsin,
        u16* __restrict__ q_r, u16* __restrict__ k_r, u16* __restrict__ v_r){
  int row = blockIdx.x;              // b*2048+tok
  int tok = row & 2047;
  int t = threadIdx.x;
  int d0 = t*4;
  int h = d0 >> 6, wd = d0 & 63, i0 = wd >> 1;
  const u16* base = QKV + (size_t)row*3072;
  size_t ob = (((size_t)(row>>11)*16 + h)*2048 + (size_t)tok)*64 + wd;
  float c0 = fcos[tok*32+i0],   s0 = fsin[tok*32+i0];
  float c1 = fcos[tok*32+i0+1], s1 = fsin[tok*32+i0+1];
  const u16* qp = base + d0;
  float x0=b2f(qp[0]), x1=b2f(qp[1]), x2=b2f(qp[2]), x3=b2f(qp[3]);
  q_r[ob]   = f2b((x0*c0-x1*s0)*SCALE_Q_LOG2E);
  q_r[ob+1] = f2b((x0*s0+x1*c0)*SCALE_Q_LOG2E);
  q_r[ob+2] = f2b((x2*c1-x3*s1)*SCALE_Q_LOG2E);
  q_r[ob+3] = f2b((x2*s1+x3*c1)*SCALE_Q_LOG2E);
  const u16* kp = base + 1024 + d0;
  x0=b2f(kp[0]); x1=b2f(kp[1]); x2=b2f(kp[2]); x3=b2f(kp[3]);
  k_r[ob]   = f2b(x0*c0-x1*s0);
  k_r[ob+1] = f2b(x0*s0+x1*c0);
  k_r[ob+2] = f2b(x2*c1-x3*s1);
  k_r[ob+3] = f2b(x2*s1+x3*c1);
  const u16* vp = base + 2048 + d0;
  v_r[ob]=vp[0]; v_r[ob+1]=vp[1]; v_r[ob+2]=vp[2]; v_r[ob+3]=vp[3];
}

// ---------------- flash attention: one KV-tile processing step (S^T formulation) ----------------
static __device__ __forceinline__ void flash_tile(
    const u16* __restrict__ Ksb, const u16* __restrict__ Vsb,
    bf16x8 qf0, bf16x8 qf1, int k0, int q, bool diag,
    int lg, int ln, float& mi, float& li, f32x4* oaccT){
  f32x4 sv[4];
  #pragma unroll
  for (int ni=0;ni<4;ni++){
    bf16x8 kf0 = *(const bf16x8*)&Ksb[(ni*16+ln)*72 + lg*8];
    bf16x8 kf1 = *(const bf16x8*)&Ksb[(ni*16+ln)*72 + 32 + lg*8];
    f32x4 z = {};
    z = __builtin_amdgcn_mfma_f32_16x16x32_bf16(kf0, qf0, z, 0,0,0);
    z = __builtin_amdgcn_mfma_f32_16x16x32_bf16(kf1, qf1, z, 0,0,0);
    sv[ni] = z;
  }
  float rm = -1e30f;
  if (diag){
    #pragma unroll
    for (int ni=0;ni<4;ni++)
      #pragma unroll
      for (int r=0;r<4;r++){
        float xs = sv[ni][r];
        if (k0+ni*16+lg*4+r > q) xs = -1e30f;
        sv[ni][r] = xs;
        rm = fmaxf(rm, xs);
      }
  } else {
    #pragma unroll
    for (int ni=0;ni<4;ni++)
      #pragma unroll
      for (int r=0;r<4;r++) rm = fmaxf(rm, sv[ni][r]);
  }
  rm = fmaxf(rm, __shfl_xor(rm, 16, 64));
  rm = fmaxf(rm, __shfl_xor(rm, 32, 64));
  float mn = fmaxf(mi, rm);
  float alpha = exp2f(mi - mn);
  float ls = 0.f;
  s16x4 pf[4];
  #pragma unroll
  for (int ni=0;ni<4;ni++){
    float p0 = exp2f(sv[ni][0]-mn);
    float p1 = exp2f(sv[ni][1]-mn);
    float p2 = exp2f(sv[ni][2]-mn);
    float p3 = exp2f(sv[ni][3]-mn);
    ls += (p0+p1)+(p2+p3);
    s16x4 pp;
    pp[0]=(short)f2b(p0); pp[1]=(short)f2b(p1); pp[2]=(short)f2b(p2); pp[3]=(short)f2b(p3);
    pf[ni]=pp;
  }
  ls += __shfl_xor(ls, 16, 64);
  ls += __shfl_xor(ls, 32, 64);
  li = li*alpha + ls;
  mi = mn;
  #pragma unroll
  for (int dt=0; dt<4; dt++){
    f32x4 oo = oaccT[dt];
    oo[0]*=alpha; oo[1]*=alpha; oo[2]*=alpha; oo[3]*=alpha;
    #pragma unroll
    for (int ni=0;ni<4;ni++){
      s16x4 vf = *(const s16x4*)&Vsb[(dt*16+ln)*72 + ni*16 + lg*4];
      oo = mfma16bf(vf, pf[ni], oo);
    }
    oaccT[dt] = oo;
  }
}

// ---------------- flash attention, causal, HD=64; paired q-tiles {p,31-p} SHARE KV staging ----------------
__global__ __launch_bounds__(256,2) void flash_kernel(const u16* __restrict__ q_r,
        const u16* __restrict__ k_r, const u16* __restrict__ v_t, u16* __restrict__ o){
  const int S = 2048;
  int pr = blockIdx.x, bh = blockIdx.y;
  int b = bh>>4, h = bh&15;
  int t = threadIdx.x, w = t>>6, l = t&63, lg = l>>4, ln = l&15;
  __shared__ u16 Ks[2][64*72];   // [token][dim]
  __shared__ u16 Vs[2][64*72];   // [dim][token]
  const u16* qb = q_r + (size_t)bh*S*64;
  const u16* kb = k_r + (size_t)bh*S*64;
  const u16* vb = v_t + (size_t)bh*64*S;
  int rr = t>>2, p16 = (t&3)*16;
  int qlo = pr, qhi = 31-pr;
  int qAr = qlo*64 + w*16 + ln;
  int qBr = qhi*64 + w*16 + ln;
  bf16x8 qA0 = *(const bf16x8*)(qb + (size_t)qAr*64 + lg*8);
  bf16x8 qA1 = *(const bf16x8*)(qb + (size_t)qAr*64 + 32 + lg*8);
  bf16x8 qB0 = *(const bf16x8*)(qb + (size_t)qBr*64 + lg*8);
  bf16x8 qB1 = *(const bf16x8*)(qb + (size_t)qBr*64 + 32 + lg*8);
  f32x4 oA[4] = {}, oB[4] = {};
  float miA=-1e30f, liA=0.f, miB=-1e30f, liB=0.f;
  // stage tile kv=0 into buffer 0
  {
    *(bf16x8*)&Ks[0][rr*72+p16]   = *(const bf16x8*)(kb + (size_t)rr*64 + p16);
    *(bf16x8*)&Ks[0][rr*72+p16+8] = *(const bf16x8*)(kb + (size_t)rr*64 + p16 + 8);
    *(bf16x8*)&Vs[0][rr*72+p16]   = *(const bf16x8*)(vb + (size_t)rr*S + p16);
    *(bf16x8*)&Vs[0][rr*72+p16+8] = *(const bf16x8*)(vb + (size_t)rr*S + p16 + 8);
  }
  __syncthreads();
  for (int kv=0; kv<=qhi; kv++){
    int cur = kv&1;
    int k0 = kv*64;
    bool hasnext = kv < qhi;
    bf16x8 nk0, nk1, nv0, nv1;
    if (hasnext){
      int kn = k0 + 64;
      nk0 = *(const bf16x8*)(kb + (size_t)(kn+rr)*64 + p16);
      nk1 = *(const bf16x8*)(kb + (size_t)(kn+rr)*64 + p16 + 8);
      nv0 = *(const bf16x8*)(vb + (size_t)rr*S + kn + p16);
      nv1 = *(const bf16x8*)(vb + (size_t)rr*S + kn + p16 + 8);
    }
    if (kv <= qlo)
      flash_tile(Ks[cur], Vs[cur], qA0, qA1, k0, qAr, kv==qlo, lg, ln, miA, liA, oA);
    flash_tile(Ks[cur], Vs[cur], qB0, qB1, k0, qBr, kv==qhi, lg, ln, miB, liB, oB);
    if (hasnext){
      int nb = cur^1;
      *(bf16x8*)&Ks[nb][rr*72+p16]   = nk0;
      *(bf16x8*)&Ks[nb][rr*72+p16+8] = nk1;
      *(bf16x8*)&Vs[nb][rr*72+p16]   = nv0;
      *(bf16x8*)&Vs[nb][rr*72+p16+8] = nv1;
    }
    __syncthreads();
  }
  // epilogues: lane writes 4 consecutive dims for its token
  {
    u16* ob = o + ((size_t)(b*S+qAr))*1024 + h*64 + lg*4;
    #pragma unroll
    for (int dt=0; dt<4; dt++){
      u16 a0=f2b(oA[dt][0]/liA), a1=f2b(oA[dt][1]/liA);
      u16 a2=f2b(oA[dt][2]/liA), a3=f2b(oA[dt][3]/liA);
      uint2 pv; pv.x = (unsigned)a0 | ((unsigned)a1<<16); pv.y = (unsigned)a2 | ((unsigned)a3<<16);
      *(uint2*)(ob + dt*16) = pv;
    }
  }
  {
    u16* ob = o + ((size_t)(b*S+qBr))*1024 + h*64 + lg*4;
    #pragma unroll
    for (int dt=0; dt<4; dt++){
      u16 a0=f2b(oB[dt][0]/liB), a1=f2b(oB[dt][1]/liB);
      u16 a2=f2b(oB[dt][2]/liB), a3=f2b(oB[dt][3]/liB);
      uint2 pv; pv.x = (unsigned)a0 | ((unsigned)a1<<16); pv.y = (unsigned)a2 | ((unsigned)a3<<16);
      *(uint2*)(ob + dt*16) = pv;
    }
  }
}

// ---------------- out = x (+ rw * (h + y) on selected rows), f32 out ----------------
__global__ __launch_bounds__(256) void final_kernel(const float* __restrict__ x, const float* __restrict__ h,
        const u16* __restrict__ y, const int* __restrict__ inv, const float* __restrict__ rw,
        float* __restrict__ out){
  int row = blockIdx.x;
  int b = row>>12;
  int t = threadIdx.x, d0 = t*4;
  float4 xv = *(const float4*)(x + (size_t)row*1024 + d0);
  float4* op = (float4*)(out + (size_t)row*1024 + d0);
  int j = inv[row];
  if (j < 0){ *op = xv; return; }
  int fr = b*2048 + j;
  float wgt = rw[fr];
  float4 hv = *(const float4*)(h + (size_t)fr*1024 + d0);
  uint2 yv = *(const uint2*)(y + (size_t)fr*1024 + d0);
  float y0=b2f((u16)(yv.x&0xffffu)), y1=b2f((u16)(yv.x>>16)), y2=b2f((u16)(yv.y&0xffffu)), y3=b2f((u16)(yv.y>>16));
  float4 ov;
  ov.x = xv.x + wgt*(hv.x + y0);
  ov.y = xv.y + wgt*(hv.y + y1);
  ov.z = xv.z + wgt*(hv.z + y2);
  ov.w = xv.w + wgt*(hv.w + y3);
  *op = ov;
}

extern "C" void kernel_launch(void* const* d_in, const int* in_sizes, int n_in,
                              void* d_out, int out_size, void* d_ws, size_t ws_size,
                              hipStream_t stream) {
  (void)in_sizes; (void)n_in; (void)out_size; (void)ws_size;
  const float* x     = (const float*)d_in[0];
  const float* fcos  = (const float*)d_in[2];
  const float* fsin  = (const float*)d_in[3];
  const float* wr    = (const float*)d_in[4];
  const float* anorm = (const float*)d_in[5];
  const float* wq    = (const float*)d_in[6];
  const float* wk    = (const float*)d_in[7];
  const float* wv    = (const float*)d_in[8];
  const float* wo    = (const float*)d_in[9];
  const float* fnorm = (const float*)d_in[10];
  const float* w1    = (const float*)d_in[11];
  const float* w2    = (const float*)d_in[12];
  const float* w3    = (const float*)d_in[13];
  float* out = (float*)d_out;

  char* W = (char*)d_ws;
  const size_t MB = 1024*1024;
  u16* WqkvT = (u16*)(W + 0);          // 6 MB
  u16* WoT   = (u16*)(W + 6*MB);       // 2 MB
  u16* W13T  = (u16*)(W + 8*MB);       // 16 MB (silu-interleaved)
  u16* W2T   = (u16*)(W + 24*MB);      // 8 MB
  u16* xn    = (u16*)(W + 32*MB);      // 8 MB  (dead after QKV gemm)
  u16* QKV   = (u16*)(W + 40*MB);      // 24 MB (dead after rope)
  u16* q_r   = (u16*)(W + 64*MB);      // 8 MB
  u16* k_r   = (u16*)(W + 72*MB);      // 8 MB
  u16* v_r   = (u16*)(W + 80*MB);      // 8 MB  (dead after v-transpose)
  u16* v_t   = (u16*)(W + 88*MB);      // 8 MB
  u16* attno = (u16*)(W + 96*MB);      // 8 MB  (dead after o-proj)
  float* hbuf= (float*)(W + 104*MB);   // 16 MB f32 (live till final)
  u16* hn    = (u16*)(W + 120*MB);     // 8 MB  (dead after FFN13)
  u16* g     = (u16*)(W + 128*MB);     // 32 MB
  u16* ybuf  = (u16*)(W + 32*MB);      // 8 MB overlay on dead xn
  float* logits = (float*)(W + 160*MB);            // 32 KB
  int*   sel    = (int*)(W + 160*MB + 64*1024);    // 16 KB
  float* rw     = (float*)(W + 160*MB + 96*1024);  // 16 KB
  int*   inv    = (int*)(W + 160*MB + 128*1024);   // 32 KB

  prep_weights<<<16384, 256, 0, stream>>>(wq, wk, wv, wo, w1, w3, w2, WqkvT, WoT, W13T, W2T);
  router_kernel<<<2048, 256, 0, stream>>>(x, wr, logits);
  topk_kernel<<<2, 1024, 0, stream>>>(logits, sel, rw, inv);
  rmsnorm_kernel<<<4096, 256, 0, stream>>>(x, anorm, sel, xn);
  gemm_bt<128,64,u16><<<dim3(24,32), 256, 0, stream>>>(xn, WqkvT, QKV, nullptr, nullptr, 4096, 3072, 1024);
  rope_kernel<<<4096, 256, 0, stream>>>(QKV, fcos, fsin, q_r, k_r, v_r);
  transpose_bf16<<<dim3(2,64,32), dim3(32,8), 0, stream>>>(v_r, v_t, 2048, 64);
  flash_kernel<<<dim3(16,32), 256, 0, stream>>>(q_r, k_r, v_t, attno);
  gemm_bt<64,64,float><<<dim3(16,32), 256, 0, stream>>>(attno, WoT, hbuf, x, sel, 4096, 1024, 1024);
  rmsnorm_kernel<<<4096, 256, 0, stream>>>(hbuf, fnorm, nullptr, hn);
  gemm13<<<dim3(64,32), 256, 0, stream>>>(hn, W13T, g, 1024);
  gemm_bt<64,64,u16><<<dim3(16,32), 256, 0, stream>>>(g, W2T, ybuf, nullptr, nullptr, 4096, 1024, 4096);
  final_kernel<<<8192, 256, 0, stream>>>(x, hbuf, ybuf, inv, rw, out);
}